// Round 6
// baseline (67.484 us; speedup 1.0000x reference)
//
#include <hip/hip_runtime.h>
#include <cmath>

#define B_ 4
#define N_ 512
#define F_ 128
#define BN_ (B_*N_)   // 2048

__device__ __forceinline__ float elu_f(float x) {
    return fmaxf(x, __expf(fminf(x, 0.f)) - 1.f);
}

// ---------------------------------------------------------------------------
// Kernel A: Hi = H @ dW1[:F] + db1 (bias folded), EHi = exp(Hi),
//           HjT[b][f][n] = (H @ dW1[F:])^T.
// 4 rows/block, 256 threads: f = t&127, kh = t>>7 owns a K-half.
// ---------------------------------------------------------------------------
__global__ __launch_bounds__(256) void k_lin1(
    const float* __restrict__ H, const float* __restrict__ dW1,
    const float* __restrict__ db1,
    float* __restrict__ Hi, float* __restrict__ EHi, float* __restrict__ HjT) {
    __shared__ float sH[4][F_];
    __shared__ float sPA[4][F_], sPB[4][F_];
    const int t = threadIdx.x;
    const int f = t & 127;
    const int kh = t >> 7;               // 0/1 K-half
    const int row0 = blockIdx.x * 4;

    #pragma unroll
    for (int p = 0; p < 2; ++p) {
        const int idx = t + p * 256;
        sH[idx >> 7][idx & 127] = H[(size_t)(row0 + (idx >> 7)) * F_ + (idx & 127)];
    }
    __syncthreads();

    float accA[4] = {0.f,0.f,0.f,0.f}, accB[4] = {0.f,0.f,0.f,0.f};
    const int k0 = kh * 64;
    #pragma unroll 4
    for (int k = k0; k < k0 + 64; ++k) {
        const float wa = dW1[(size_t)k * F_ + f];
        const float wb = dW1[(size_t)(F_ + k) * F_ + f];
        #pragma unroll
        for (int r = 0; r < 4; ++r) {
            accA[r] = fmaf(sH[r][k], wa, accA[r]);
            accB[r] = fmaf(sH[r][k], wb, accB[r]);
        }
    }
    if (kh == 1) {
        #pragma unroll
        for (int r = 0; r < 4; ++r) { sPA[r][f] = accA[r]; sPB[r][f] = accB[r]; }
    }
    __syncthreads();
    if (kh == 0) {
        const float bias = db1[f];
        const int b  = row0 >> 9;
        const int n0 = row0 & 511;
        #pragma unroll
        for (int r = 0; r < 4; ++r) {
            const float hv_ = accA[r] + sPA[r][f] + bias;
            Hi [(size_t)(row0 + r) * F_ + f] = hv_;
            EHi[(size_t)(row0 + r) * F_ + f] = __expf(hv_);
        }
        float4 hv;
        hv.x = accB[0] + sPB[0][f];
        hv.y = accB[1] + sPB[1][f];
        hv.z = accB[2] + sPB[2][f];
        hv.w = accB[3] + sPB[3][f];
        *reinterpret_cast<float4*>(HjT + ((size_t)b * F_ + f) * N_ + n0) = hv;
    }
}

// ---------------------------------------------------------------------------
// Kernel B: 4 rows i per block, 512 threads (thread = j).
// Per element: elu(hi+hj) = max(x, min(Ei*Ej - 1, 0)) — no per-element exp.
// Ej = exp(hj) computed once per (f,j), shared by 4 rows. Scalar operands
// (hi, Ei, w) double-buffer-prefetched as uniform float4 chunks.
// ---------------------------------------------------------------------------
__global__ __launch_bounds__(512) void k_score(
    const float* __restrict__ Hi, const float* __restrict__ EHi,
    const float* __restrict__ HjT, const float* __restrict__ A,
    const float* __restrict__ dW2, const float* __restrict__ db2,
    float* __restrict__ maxc, float* __restrict__ degv,
    float* __restrict__ maskout) {
    __shared__ float red_mx[8][4];
    __shared__ int   red_cnt[8][4];
    const int t = threadIdx.x;            // == j
    const int lane = t & 63;
    const int w = t >> 6;                 // wave 0..7
    const int bi0 = blockIdx.x * 4;
    const int b = bi0 >> 9;

    const float* hi_base[4];
    const float* ei_base[4];
    #pragma unroll
    for (int r = 0; r < 4; ++r) {
        hi_base[r] = Hi  + (size_t)(bi0 + r) * F_;
        ei_base[r] = EHi + (size_t)(bi0 + r) * F_;
    }
    const float* __restrict__ hjp = HjT + (size_t)b * F_ * N_ + t;

    float a_r[4];
    #pragma unroll
    for (int r = 0; r < 4; ++r) a_r[r] = A[(size_t)(bi0 + r) * N_ + t];

    float acc[4] = {0.f, 0.f, 0.f, 0.f};

    auto load_chunk = [&](int c, float (&bhi)[4][4], float (&bei)[4][4],
                          float (&bw)[4], float (&bhj)[4]) {
        const int fq = c * 4;
        #pragma unroll
        for (int r = 0; r < 4; ++r) {
            const float4 h = *reinterpret_cast<const float4*>(hi_base[r] + fq);
            const float4 e = *reinterpret_cast<const float4*>(ei_base[r] + fq);
            bhi[r][0] = h.x; bhi[r][1] = h.y; bhi[r][2] = h.z; bhi[r][3] = h.w;
            bei[r][0] = e.x; bei[r][1] = e.y; bei[r][2] = e.z; bei[r][3] = e.w;
        }
        const float4 wv = *reinterpret_cast<const float4*>(dW2 + fq);
        bw[0] = wv.x; bw[1] = wv.y; bw[2] = wv.z; bw[3] = wv.w;
        #pragma unroll
        for (int s = 0; s < 4; ++s) bhj[s] = hjp[(size_t)(fq + s) * N_];
    };
    auto comp_chunk = [&](const float (&bhi)[4][4], const float (&bei)[4][4],
                          const float (&bw)[4], const float (&bhj)[4]) {
        #pragma unroll
        for (int s = 0; s < 4; ++s) {
            const float hj = bhj[s];
            const float ej = __expf(hj);
            #pragma unroll
            for (int r = 0; r < 4; ++r) {
                const float x  = bhi[r][s] + hj;
                const float e1 = fminf(fmaf(bei[r][s], ej, -1.f), 0.f);
                acc[r] = fmaf(fmaxf(x, e1), bw[s], acc[r]);
            }
        }
    };

    float Ahi[4][4], Aei[4][4], Aw[4], Ahj[4];
    float Bhi[4][4], Bei[4][4], Bw[4], Bhj[4];
    load_chunk(0, Ahi, Aei, Aw, Ahj);
    for (int c = 0; c < 32; c += 2) {
        load_chunk(c + 1, Bhi, Bei, Bw, Bhj);
        comp_chunk(Ahi, Aei, Aw, Ahj);
        if (c + 2 < 32) load_chunk(c + 2, Ahi, Aei, Aw, Ahj);
        comp_chunk(Bhi, Bei, Bw, Bhj);
    }

    #pragma unroll
    for (int r = 0; r < 4; ++r) {
        float mx = (a_r[r] > 0.1f) ? acc[r] : -INFINITY;
        int cnt = (a_r[r] > 0.f) ? 1 : 0;
        #pragma unroll
        for (int off = 1; off < 64; off <<= 1) {
            mx = fmaxf(mx, __shfl_xor(mx, off));
            cnt += __shfl_xor(cnt, off);
        }
        if (lane == 0) { red_mx[w][r] = mx; red_cnt[w][r] = cnt; }
    }
    __syncthreads();
    if (t < 4) {
        float m = -INFINITY; int c = 0;
        #pragma unroll
        for (int ww = 0; ww < 8; ++ww) {
            m = fmaxf(m, red_mx[ww][t]);
            c += red_cnt[ww][t];
        }
        const float mc = (m > -INFINITY)
                       ? 1.f / (1.f + __expf(-(m + db2[0]))) : 0.f;
        maxc[bi0 + t] = mc;
        degv[bi0 + t] = (float)c;
        maskout[bi0 + t] = (mc > 0.5f) ? 1.f : 0.f;
    }
}

// ---------------------------------------------------------------------------
// Kernel N: neighbor mean. 4 rows/block, 256 threads = 4 waves; wave w owns
// j-range [w*128, w*128+128). Mask as ballot bits in SGPRs; float2 H loads.
// ---------------------------------------------------------------------------
__global__ __launch_bounds__(256) void k_nbr(
    const float* __restrict__ A, const float* __restrict__ H,
    const float* __restrict__ degv, float* __restrict__ nf) {
    __shared__ float2 sPart[4][4][64];
    const int t = threadIdx.x;
    const int lane = t & 63;
    const int w = t >> 6;                 // wave 0..3
    const int bi0 = blockIdx.x * 4;
    const int b = bi0 >> 9;

    unsigned long long msk[2][4];
    #pragma unroll
    for (int sub = 0; sub < 2; ++sub) {
        const int jj = w * 128 + sub * 64 + lane;
        #pragma unroll
        for (int r = 0; r < 4; ++r)
            msk[sub][r] = __ballot(A[(size_t)(bi0 + r) * N_ + jj] > 0.f);
    }

    float2 acc[4];
    #pragma unroll
    for (int r = 0; r < 4; ++r) acc[r] = make_float2(0.f, 0.f);

    const float* hb = H + ((size_t)b * N_ + w * 128) * F_ + 2 * lane;
    #pragma unroll
    for (int sub = 0; sub < 2; ++sub) {
        #pragma unroll 8
        for (int j = 0; j < 64; ++j) {
            const float2 h2 = *reinterpret_cast<const float2*>(
                hb + (size_t)(sub * 64 + j) * F_);
            #pragma unroll
            for (int r = 0; r < 4; ++r) {
                const float m = ((msk[sub][r] >> j) & 1ull) ? 1.f : 0.f;
                acc[r].x = fmaf(m, h2.x, acc[r].x);
                acc[r].y = fmaf(m, h2.y, acc[r].y);
            }
        }
    }
    #pragma unroll
    for (int r = 0; r < 4; ++r) sPart[w][r][lane] = acc[r];
    __syncthreads();
    if (w == 0) {
        #pragma unroll
        for (int r = 0; r < 4; ++r) {
            float2 s = sPart[0][r][lane];
            #pragma unroll
            for (int ww = 1; ww < 4; ++ww) {
                s.x += sPart[ww][r][lane].x;
                s.y += sPart[ww][r][lane].y;
            }
            const float d = fmaxf(degv[bi0 + r], 1.f);
            float2 o; o.x = s.x / d; o.y = s.y / d;
            *reinterpret_cast<float2*>(nf + (size_t)(bi0 + r) * F_ + 2 * lane) = o;
        }
    }
}

// ---------------------------------------------------------------------------
// Kernel C: res = elu([H,nf,maxc] @ rW1 + rb1) @ rW2 + rb2; select per row.
// 4 rows/block, 512 blocks, 512 threads: f = t&127, kq = t>>7 K-quarter.
// ---------------------------------------------------------------------------
__global__ __launch_bounds__(512) void k_mlp(
    const float* __restrict__ H, const float* __restrict__ nf,
    const float* __restrict__ maxc, const float* __restrict__ degv,
    const float* __restrict__ rW1, const float* __restrict__ rb1,
    const float* __restrict__ rW2, const float* __restrict__ rb2,
    float* __restrict__ out) {
    __shared__ float sP[3][4][F_];
    __shared__ float sL1[4][F_];
    const int t  = threadIdx.x;
    const int f  = t & 127;
    const int kq = t >> 7;                // 0..3
    const int row0 = blockIdx.x * 4;

    const float* __restrict__ srcbase = (kq < 2) ? H : nf;
    const int koff = (kq < 2) ? (kq * 64) : (kq * 64 - 128);
    const float* __restrict__ s0 = srcbase + (size_t)(row0 + 0) * F_ + koff;
    const float* __restrict__ s1 = srcbase + (size_t)(row0 + 1) * F_ + koff;
    const float* __restrict__ s2 = srcbase + (size_t)(row0 + 2) * F_ + koff;
    const float* __restrict__ s3 = srcbase + (size_t)(row0 + 3) * F_ + koff;

    float acc[4];
    {
        const float bias = rb1[f];
        #pragma unroll
        for (int r = 0; r < 4; ++r) acc[r] = (kq == 0) ? bias : 0.f;
    }
    const int kg0 = kq * 64;
    #pragma unroll 4
    for (int kk = 0; kk < 64; kk += 4) {
        const float4 c0 = *reinterpret_cast<const float4*>(s0 + kk);
        const float4 c1 = *reinterpret_cast<const float4*>(s1 + kk);
        const float4 c2 = *reinterpret_cast<const float4*>(s2 + kk);
        const float4 c3 = *reinterpret_cast<const float4*>(s3 + kk);
        const float* c0p = &c0.x; const float* c1p = &c1.x;
        const float* c2p = &c2.x; const float* c3p = &c3.x;
        #pragma unroll
        for (int s = 0; s < 4; ++s) {
            const float wv = rW1[(size_t)(kg0 + kk + s) * F_ + f];
            acc[0] = fmaf(c0p[s], wv, acc[0]);
            acc[1] = fmaf(c1p[s], wv, acc[1]);
            acc[2] = fmaf(c2p[s], wv, acc[2]);
            acc[3] = fmaf(c3p[s], wv, acc[3]);
        }
    }
    if (kq == 3) {                        // k = 256: maxc column
        const float w256 = rW1[(size_t)256 * F_ + f];
        #pragma unroll
        for (int r = 0; r < 4; ++r)
            acc[r] = fmaf(maxc[row0 + r], w256, acc[r]);
    }
    if (kq > 0) {
        #pragma unroll
        for (int r = 0; r < 4; ++r) sP[kq - 1][r][f] = acc[r];
    }
    __syncthreads();
    if (kq == 0) {
        #pragma unroll
        for (int r = 0; r < 4; ++r)
            sL1[r][f] = elu_f(acc[r] + sP[0][r][f] + sP[1][r][f] + sP[2][r][f]);
    }
    __syncthreads();

    float acc2[4];
    {
        const float bias2 = rb2[f];
        #pragma unroll
        for (int r = 0; r < 4; ++r) acc2[r] = (kq == 0) ? bias2 : 0.f;
    }
    const int m0k = kq * 32;
    #pragma unroll 4
    for (int kk = 0; kk < 32; kk += 4) {
        const float4 l0 = *reinterpret_cast<const float4*>(&sL1[0][m0k + kk]);
        const float4 l1 = *reinterpret_cast<const float4*>(&sL1[1][m0k + kk]);
        const float4 l2 = *reinterpret_cast<const float4*>(&sL1[2][m0k + kk]);
        const float4 l3 = *reinterpret_cast<const float4*>(&sL1[3][m0k + kk]);
        const float* l0p = &l0.x; const float* l1p = &l1.x;
        const float* l2p = &l2.x; const float* l3p = &l3.x;
        #pragma unroll
        for (int s = 0; s < 4; ++s) {
            const float wv = rW2[(size_t)(m0k + kk + s) * F_ + f];
            acc2[0] = fmaf(l0p[s], wv, acc2[0]);
            acc2[1] = fmaf(l1p[s], wv, acc2[1]);
            acc2[2] = fmaf(l2p[s], wv, acc2[2]);
            acc2[3] = fmaf(l3p[s], wv, acc2[3]);
        }
    }
    if (kq > 0) {
        #pragma unroll
        for (int r = 0; r < 4; ++r) sP[kq - 1][r][f] = acc2[r];
    }
    __syncthreads();
    if (kq == 0) {
        #pragma unroll
        for (int r = 0; r < 4; ++r) {
            const int row = row0 + r;
            const float res = acc2[r] + sP[0][r][f] + sP[1][r][f] + sP[2][r][f];
            const bool upd = (maxc[row] > 0.5f) && (degv[row] > 0.f);
            out[(size_t)row * F_ + f] = upd ? res : H[(size_t)row * F_ + f];
        }
    }
}

// ---------------------------------------------------------------------------
extern "C" void kernel_launch(void* const* d_in, const int* in_sizes, int n_in,
                              void* d_out, int out_size, void* d_ws, size_t ws_size,
                              hipStream_t stream) {
    const float* H   = (const float*)d_in[0];
    const float* A   = (const float*)d_in[1];
    const float* dW1 = (const float*)d_in[2];
    const float* db1 = (const float*)d_in[3];
    const float* dW2 = (const float*)d_in[4];
    const float* db2 = (const float*)d_in[5];
    const float* rW1 = (const float*)d_in[6];
    const float* rb1 = (const float*)d_in[7];
    const float* rW2 = (const float*)d_in[8];
    const float* rb2 = (const float*)d_in[9];

    float* ws   = (float*)d_ws;
    float* Hi   = ws;                      // [BN][F]
    float* EHi  = Hi  + BN_ * F_;          // [BN][F] exp(Hi)
    float* HjT  = EHi + BN_ * F_;          // [B][F][N]
    float* maxc = HjT + BN_ * F_;          // [BN]
    float* degv = maxc + BN_;              // [BN]
    float* nf   = degv + BN_;              // [BN][F]

    float* out      = (float*)d_out;       // [BN][F] H_resolved
    float* mask_out = out + BN_ * F_;      // [BN] contra_mask as 0/1

    k_lin1 <<<BN_ / 4, 256, 0, stream>>>(H, dW1, db1, Hi, EHi, HjT);
    k_score<<<BN_ / 4, 512, 0, stream>>>(Hi, EHi, HjT, A, dW2, db2, maxc, degv, mask_out);
    k_nbr  <<<BN_ / 4, 256, 0, stream>>>(A, H, degv, nf);
    k_mlp  <<<BN_ / 4, 512, 0, stream>>>(H, nf, maxc, degv, rW1, rb1, rW2, rb2, out);
}

// Round 7
// 53.924 us; speedup vs baseline: 1.2515x; 1.2515x over previous
//
#include <hip/hip_runtime.h>
#include <cmath>

#define B_ 4
#define N_ 512
#define F_ 128
#define BN_ (B_*N_)   // 2048

__device__ __forceinline__ float elu_f(float x) {
    return fmaxf(x, __expf(fminf(x, 0.f)) - 1.f);
}

// ---------------------------------------------------------------------------
// Kernel A: Hi = H @ dW1[:F] + db1 (bias folded), EHi = exp(Hi),
//           HjT[b][f][n] = (H @ dW1[F:])^T.
// 4 rows/block, 256 threads: f = t&127, kh = t>>7 owns a K-half.
// ---------------------------------------------------------------------------
__global__ __launch_bounds__(256) void k_lin1(
    const float* __restrict__ H, const float* __restrict__ dW1,
    const float* __restrict__ db1,
    float* __restrict__ Hi, float* __restrict__ EHi, float* __restrict__ HjT) {
    __shared__ float sH[4][F_];
    __shared__ float sPA[4][F_], sPB[4][F_];
    const int t = threadIdx.x;
    const int f = t & 127;
    const int kh = t >> 7;               // 0/1 K-half
    const int row0 = blockIdx.x * 4;

    #pragma unroll
    for (int p = 0; p < 2; ++p) {
        const int idx = t + p * 256;
        sH[idx >> 7][idx & 127] = H[(size_t)(row0 + (idx >> 7)) * F_ + (idx & 127)];
    }
    __syncthreads();

    float accA[4] = {0.f,0.f,0.f,0.f}, accB[4] = {0.f,0.f,0.f,0.f};
    const int k0 = kh * 64;
    #pragma unroll 4
    for (int k = k0; k < k0 + 64; ++k) {
        const float wa = dW1[(size_t)k * F_ + f];
        const float wb = dW1[(size_t)(F_ + k) * F_ + f];
        #pragma unroll
        for (int r = 0; r < 4; ++r) {
            accA[r] = fmaf(sH[r][k], wa, accA[r]);
            accB[r] = fmaf(sH[r][k], wb, accB[r]);
        }
    }
    if (kh == 1) {
        #pragma unroll
        for (int r = 0; r < 4; ++r) { sPA[r][f] = accA[r]; sPB[r][f] = accB[r]; }
    }
    __syncthreads();
    if (kh == 0) {
        const float bias = db1[f];
        const int b  = row0 >> 9;
        const int n0 = row0 & 511;
        #pragma unroll
        for (int r = 0; r < 4; ++r) {
            const float hv_ = accA[r] + sPA[r][f] + bias;
            Hi [(size_t)(row0 + r) * F_ + f] = hv_;
            EHi[(size_t)(row0 + r) * F_ + f] = __expf(hv_);
        }
        float4 hv;
        hv.x = accB[0] + sPB[0][f];
        hv.y = accB[1] + sPB[1][f];
        hv.z = accB[2] + sPB[2][f];
        hv.w = accB[3] + sPB[3][f];
        *reinterpret_cast<float4*>(HjT + ((size_t)b * F_ + f) * N_ + n0) = hv;
    }
}

// ---------------------------------------------------------------------------
// Kernel B: 4 rows i per block, 512 threads (thread = j).
// Uniform operands (hi, Ei=exp(hi), w) staged once in LDS as float4 structs,
// read per f-quad with 9 uniform ds_read_b128 (broadcast = conflict-free).
// Per element: elu(x) = max(x, min(Ei*Ej-1, 0)), Ej = exp(hj) shared by 4
// rows. hj VMEM loads double-buffered in pairs of quads.
// ---------------------------------------------------------------------------
__global__ __launch_bounds__(512) void k_score(
    const float* __restrict__ Hi, const float* __restrict__ EHi,
    const float* __restrict__ HjT, const float* __restrict__ A,
    const float* __restrict__ dW2, const float* __restrict__ db2,
    float* __restrict__ maxc, float* __restrict__ degv,
    float* __restrict__ maskout) {
    __shared__ float4 sU[32][9];          // [quad][0..3]=hi rows,[4..7]=Ei rows,[8]=w
    __shared__ float red_mx[8][4];
    __shared__ int   red_cnt[8][4];
    const int t = threadIdx.x;            // == j
    const int lane = t & 63;
    const int w = t >> 6;                 // wave 0..7
    const int bi0 = blockIdx.x * 4;
    const int b = bi0 >> 9;

    if (t < 288) {
        const int q  = t / 9;
        const int sl = t - q * 9;
        const float* src = (sl < 4) ? (Hi  + (size_t)(bi0 + sl)     * F_ + 4 * q)
                         : (sl < 8) ? (EHi + (size_t)(bi0 + sl - 4) * F_ + 4 * q)
                                    : (dW2 + 4 * q);
        sU[q][sl] = *reinterpret_cast<const float4*>(src);
    }
    float a_r[4];
    #pragma unroll
    for (int r = 0; r < 4; ++r) a_r[r] = A[(size_t)(bi0 + r) * N_ + t];

    const float* __restrict__ hjp = HjT + (size_t)b * F_ * N_ + t;
    float hjA[4], hjB[4];
    #pragma unroll
    for (int s = 0; s < 4; ++s) hjA[s] = hjp[(size_t)s * N_];
    __syncthreads();

    float acc0 = 0.f, acc1 = 0.f, acc2 = 0.f, acc3 = 0.f;

    auto elem = [&](float hi, float ei, float wv, float hj, float ej, float& acc) {
        const float x  = hi + hj;
        const float t0 = fminf(fmaf(ei, ej, -1.f), 0.f);
        acc = fmaf(fmaxf(x, t0), wv, acc);
    };
    auto compQ = [&](int q, const float (&hjv)[4]) {
        const float4 h0 = sU[q][0], h1 = sU[q][1], h2 = sU[q][2], h3 = sU[q][3];
        const float4 e0 = sU[q][4], e1 = sU[q][5], e2 = sU[q][6], e3 = sU[q][7];
        const float4 wq = sU[q][8];
        { const float hj = hjv[0], ej = __expf(hj);
          elem(h0.x, e0.x, wq.x, hj, ej, acc0); elem(h1.x, e1.x, wq.x, hj, ej, acc1);
          elem(h2.x, e2.x, wq.x, hj, ej, acc2); elem(h3.x, e3.x, wq.x, hj, ej, acc3); }
        { const float hj = hjv[1], ej = __expf(hj);
          elem(h0.y, e0.y, wq.y, hj, ej, acc0); elem(h1.y, e1.y, wq.y, hj, ej, acc1);
          elem(h2.y, e2.y, wq.y, hj, ej, acc2); elem(h3.y, e3.y, wq.y, hj, ej, acc3); }
        { const float hj = hjv[2], ej = __expf(hj);
          elem(h0.z, e0.z, wq.z, hj, ej, acc0); elem(h1.z, e1.z, wq.z, hj, ej, acc1);
          elem(h2.z, e2.z, wq.z, hj, ej, acc2); elem(h3.z, e3.z, wq.z, hj, ej, acc3); }
        { const float hj = hjv[3], ej = __expf(hj);
          elem(h0.w, e0.w, wq.w, hj, ej, acc0); elem(h1.w, e1.w, wq.w, hj, ej, acc1);
          elem(h2.w, e2.w, wq.w, hj, ej, acc2); elem(h3.w, e3.w, wq.w, hj, ej, acc3); }
    };
    auto loadhj = [&](int q, float (&buf)[4]) {
        #pragma unroll
        for (int s = 0; s < 4; ++s) buf[s] = hjp[(size_t)(4 * q + s) * N_];
    };

    for (int q = 0; q < 32; q += 2) {
        loadhj(q + 1, hjB);
        compQ(q, hjA);
        if (q + 2 < 32) loadhj(q + 2, hjA);
        compQ(q + 1, hjB);
    }

    float accv[4] = {acc0, acc1, acc2, acc3};
    #pragma unroll
    for (int r = 0; r < 4; ++r) {
        float mx = (a_r[r] > 0.1f) ? accv[r] : -INFINITY;
        int cnt = (a_r[r] > 0.f) ? 1 : 0;
        #pragma unroll
        for (int off = 1; off < 64; off <<= 1) {
            mx = fmaxf(mx, __shfl_xor(mx, off));
            cnt += __shfl_xor(cnt, off);
        }
        if (lane == 0) { red_mx[w][r] = mx; red_cnt[w][r] = cnt; }
    }
    __syncthreads();
    if (t < 4) {
        float m = -INFINITY; int c = 0;
        #pragma unroll
        for (int ww = 0; ww < 8; ++ww) {
            m = fmaxf(m, red_mx[ww][t]);
            c += red_cnt[ww][t];
        }
        const float mc = (m > -INFINITY)
                       ? 1.f / (1.f + __expf(-(m + db2[0]))) : 0.f;
        maxc[bi0 + t] = mc;
        degv[bi0 + t] = (float)c;
        maskout[bi0 + t] = (mc > 0.5f) ? 1.f : 0.f;
    }
}

// ---------------------------------------------------------------------------
// Kernel N: neighbor mean. 4 rows/block, 256 threads = 4 waves; wave w owns
// j-range [w*128, w*128+128). Mask as ballot bits in SGPRs; float2 H loads.
// ---------------------------------------------------------------------------
__global__ __launch_bounds__(256) void k_nbr(
    const float* __restrict__ A, const float* __restrict__ H,
    const float* __restrict__ degv, float* __restrict__ nf) {
    __shared__ float2 sPart[4][4][64];
    const int t = threadIdx.x;
    const int lane = t & 63;
    const int w = t >> 6;                 // wave 0..3
    const int bi0 = blockIdx.x * 4;
    const int b = bi0 >> 9;

    unsigned long long msk[2][4];
    #pragma unroll
    for (int sub = 0; sub < 2; ++sub) {
        const int jj = w * 128 + sub * 64 + lane;
        #pragma unroll
        for (int r = 0; r < 4; ++r)
            msk[sub][r] = __ballot(A[(size_t)(bi0 + r) * N_ + jj] > 0.f);
    }

    float2 acc[4];
    #pragma unroll
    for (int r = 0; r < 4; ++r) acc[r] = make_float2(0.f, 0.f);

    const float* hb = H + ((size_t)b * N_ + w * 128) * F_ + 2 * lane;
    #pragma unroll
    for (int sub = 0; sub < 2; ++sub) {
        #pragma unroll 8
        for (int j = 0; j < 64; ++j) {
            const float2 h2 = *reinterpret_cast<const float2*>(
                hb + (size_t)(sub * 64 + j) * F_);
            #pragma unroll
            for (int r = 0; r < 4; ++r) {
                const float m = ((msk[sub][r] >> j) & 1ull) ? 1.f : 0.f;
                acc[r].x = fmaf(m, h2.x, acc[r].x);
                acc[r].y = fmaf(m, h2.y, acc[r].y);
            }
        }
    }
    #pragma unroll
    for (int r = 0; r < 4; ++r) sPart[w][r][lane] = acc[r];
    __syncthreads();
    if (w == 0) {
        #pragma unroll
        for (int r = 0; r < 4; ++r) {
            float2 s = sPart[0][r][lane];
            #pragma unroll
            for (int ww = 1; ww < 4; ++ww) {
                s.x += sPart[ww][r][lane].x;
                s.y += sPart[ww][r][lane].y;
            }
            const float d = fmaxf(degv[bi0 + r], 1.f);
            float2 o; o.x = s.x / d; o.y = s.y / d;
            *reinterpret_cast<float2*>(nf + (size_t)(bi0 + r) * F_ + 2 * lane) = o;
        }
    }
}

// ---------------------------------------------------------------------------
// Kernel C (round-4 structure): res = elu([H,nf,maxc]@rW1+rb1)@rW2+rb2.
// 4 rows/block, 512 blocks, 512 threads: f = t&127, kq = t>>7 K-quarter.
// Inputs staged in LDS (sC), float4 LDS reads, split-K partial reduce.
// ---------------------------------------------------------------------------
__global__ __launch_bounds__(512) void k_mlp(
    const float* __restrict__ H, const float* __restrict__ nf,
    const float* __restrict__ maxc, const float* __restrict__ degv,
    const float* __restrict__ rW1, const float* __restrict__ rb1,
    const float* __restrict__ rW2, const float* __restrict__ rb2,
    float* __restrict__ out) {
    __shared__ float sC[4][260];
    __shared__ float sP[3][4][F_];
    __shared__ float sL1[4][F_];
    const int t  = threadIdx.x;
    const int f  = t & 127;
    const int kq = t >> 7;                // 0..3
    const int row0 = blockIdx.x * 4;

    #pragma unroll
    for (int p = 0; p < 2; ++p) {
        const int idx = t + p * 512;      // 0..1023
        const int r = idx >> 8;           // 0..3
        const int c = idx & 255;          // 0..255
        sC[r][c] = (c < F_) ? H [(size_t)(row0 + r) * F_ + c]
                            : nf[(size_t)(row0 + r) * F_ + (c - F_)];
    }
    if (t < 4) sC[t][2 * F_] = maxc[row0 + t];
    __syncthreads();

    // ---- layer 1: [4 x 257] @ [257 x 128], K split across kq ----
    float acc[4];
    #pragma unroll
    for (int r = 0; r < 4; ++r) acc[r] = (kq == 0) ? rb1[f] : 0.f;
    const int k0 = kq * 64;
    const int k1 = (kq == 3) ? 257 : (k0 + 64);
    #pragma unroll 4
    for (int k = k0; k < k1; ++k) {
        const float wv = rW1[(size_t)k * F_ + f];
        #pragma unroll
        for (int r = 0; r < 4; ++r) acc[r] = fmaf(sC[r][k], wv, acc[r]);
    }
    if (kq > 0) {
        #pragma unroll
        for (int r = 0; r < 4; ++r) sP[kq - 1][r][f] = acc[r];
    }
    __syncthreads();
    if (kq == 0) {
        #pragma unroll
        for (int r = 0; r < 4; ++r)
            sL1[r][f] = elu_f(acc[r] + sP[0][r][f] + sP[1][r][f] + sP[2][r][f]);
    }
    __syncthreads();

    // ---- layer 2: [4 x 128] @ [128 x 128], K split across kq ----
    float acc2[4];
    #pragma unroll
    for (int r = 0; r < 4; ++r) acc2[r] = (kq == 0) ? rb2[f] : 0.f;
    const int m0k = kq * 32;
    #pragma unroll 4
    for (int k = m0k; k < m0k + 32; ++k) {
        const float wv = rW2[(size_t)k * F_ + f];
        #pragma unroll
        for (int r = 0; r < 4; ++r) acc2[r] = fmaf(sL1[r][k], wv, acc2[r]);
    }
    if (kq > 0) {
        #pragma unroll
        for (int r = 0; r < 4; ++r) sP[kq - 1][r][f] = acc2[r];
    }
    __syncthreads();
    if (kq == 0) {
        #pragma unroll
        for (int r = 0; r < 4; ++r) {
            const int row = row0 + r;
            const float res = acc2[r] + sP[0][r][f] + sP[1][r][f] + sP[2][r][f];
            const bool upd = (maxc[row] > 0.5f) && (degv[row] > 0.f);
            out[(size_t)row * F_ + f] = upd ? res : sC[r][f];
        }
    }
}

// ---------------------------------------------------------------------------
extern "C" void kernel_launch(void* const* d_in, const int* in_sizes, int n_in,
                              void* d_out, int out_size, void* d_ws, size_t ws_size,
                              hipStream_t stream) {
    const float* H   = (const float*)d_in[0];
    const float* A   = (const float*)d_in[1];
    const float* dW1 = (const float*)d_in[2];
    const float* db1 = (const float*)d_in[3];
    const float* dW2 = (const float*)d_in[4];
    const float* db2 = (const float*)d_in[5];
    const float* rW1 = (const float*)d_in[6];
    const float* rb1 = (const float*)d_in[7];
    const float* rW2 = (const float*)d_in[8];
    const float* rb2 = (const float*)d_in[9];

    float* ws   = (float*)d_ws;
    float* Hi   = ws;                      // [BN][F]
    float* EHi  = Hi  + BN_ * F_;          // [BN][F] exp(Hi)
    float* HjT  = EHi + BN_ * F_;          // [B][F][N]
    float* maxc = HjT + BN_ * F_;          // [BN]
    float* degv = maxc + BN_;              // [BN]
    float* nf   = degv + BN_;              // [BN][F]

    float* out      = (float*)d_out;       // [BN][F] H_resolved
    float* mask_out = out + BN_ * F_;      // [BN] contra_mask as 0/1

    k_lin1 <<<BN_ / 4, 256, 0, stream>>>(H, dW1, db1, Hi, EHi, HjT);
    k_score<<<BN_ / 4, 512, 0, stream>>>(Hi, EHi, HjT, A, dW2, db2, maxc, degv, mask_out);
    k_nbr  <<<BN_ / 4, 256, 0, stream>>>(A, H, degv, nf);
    k_mlp  <<<BN_ / 4, 512, 0, stream>>>(H, nf, maxc, degv, rW1, rb1, rW2, rb2, out);
}

// Round 9
// 53.712 us; speedup vs baseline: 1.2564x; 1.0040x over previous
//
#include <hip/hip_runtime.h>
#include <cmath>

#define B_ 4
#define N_ 512
#define F_ 128
#define BN_ (B_*N_)   // 2048

__device__ __forceinline__ float elu_f(float x) {
    return fmaxf(x, __expf(fminf(x, 0.f)) - 1.f);
}

// ---------------------------------------------------------------------------
// Kernel 1: fused lin1 + neighbor-mean. 4 rows/block, 512 threads.
//   lin1: Hi = H@dW1[:F]+db1, EHi = exp(Hi), HjT[b][f][n] = (H@dW1[F:])^T
//         (K=128 split across kq = t>>7, LDS partial reduce)
//   nbr:  nf = (A>0)-masked column mean of H; deg via __popcll(ballot),
//         so this kernel has NO dependence on the score kernel.
// ---------------------------------------------------------------------------
__global__ __launch_bounds__(512) void k_pre(
    const float* __restrict__ H, const float* __restrict__ A,
    const float* __restrict__ dW1, const float* __restrict__ db1,
    float* __restrict__ Hi, float* __restrict__ EHi, float* __restrict__ HjT,
    float* __restrict__ nf) {
    __shared__ float sH[4][F_];
    __shared__ float sPA[3][4][F_], sPB[3][4][F_];
    __shared__ float sN[3][4][F_];
    __shared__ int   sDeg[4][4];          // [jq][r]
    const int t = threadIdx.x;
    const int f = t & 127;
    const int kq = t >> 7;                // 0..3; doubles as j-quarter (jq)
    const int lane = t & 63;
    const int w = t >> 6;
    const int row0 = blockIdx.x * 4;
    const int b = row0 >> 9;
    const int n0 = row0 & 511;

    // --- nbr masks via ballot (no deps, issued first) ---
    unsigned long long msk[2][4];
    #pragma unroll
    for (int sub = 0; sub < 2; ++sub) {
        const int jj = kq * 128 + sub * 64 + lane;
        #pragma unroll
        for (int r = 0; r < 4; ++r)
            msk[sub][r] = __ballot(A[(size_t)(row0 + r) * N_ + jj] > 0.f);
    }
    if (lane == 0 && (w & 1) == 0) {
        #pragma unroll
        for (int r = 0; r < 4; ++r)
            sDeg[kq][r] = __popcll(msk[0][r]) + __popcll(msk[1][r]);
    }

    // --- lin1: stage 4 H rows (one elem per thread) ---
    sH[kq][f] = H[(size_t)(row0 + kq) * F_ + f];
    __syncthreads();

    float accA[4] = {0.f,0.f,0.f,0.f}, accB[4] = {0.f,0.f,0.f,0.f};
    const int k0 = kq * 32;
    #pragma unroll 4
    for (int k = k0; k < k0 + 32; ++k) {
        const float wa = dW1[(size_t)k * F_ + f];
        const float wb = dW1[(size_t)(F_ + k) * F_ + f];
        #pragma unroll
        for (int r = 0; r < 4; ++r) {
            accA[r] = fmaf(sH[r][k], wa, accA[r]);
            accB[r] = fmaf(sH[r][k], wb, accB[r]);
        }
    }
    if (kq > 0) {
        #pragma unroll
        for (int r = 0; r < 4; ++r) {
            sPA[kq - 1][r][f] = accA[r];
            sPB[kq - 1][r][f] = accB[r];
        }
    }
    __syncthreads();
    if (kq == 0) {
        const float bias = db1[f];
        float bsum[4];
        #pragma unroll
        for (int r = 0; r < 4; ++r) {
            const float av = accA[r] + sPA[0][r][f] + sPA[1][r][f]
                           + sPA[2][r][f] + bias;
            Hi [(size_t)(row0 + r) * F_ + f] = av;
            EHi[(size_t)(row0 + r) * F_ + f] = __expf(av);
            bsum[r] = accB[r] + sPB[0][r][f] + sPB[1][r][f] + sPB[2][r][f];
        }
        float4 hv;
        hv.x = bsum[0]; hv.y = bsum[1]; hv.z = bsum[2]; hv.w = bsum[3];
        *reinterpret_cast<float4*>(HjT + ((size_t)b * F_ + f) * N_ + n0) = hv;
    }

    // --- nbr: masked column sums over this thread's j-quarter ---
    float accN[4] = {0.f,0.f,0.f,0.f};
    const float* hb = H + ((size_t)b * N_ + kq * 128) * F_ + f;
    #pragma unroll
    for (int sub = 0; sub < 2; ++sub) {
        #pragma unroll 8
        for (int j = 0; j < 64; ++j) {
            const float h = hb[(size_t)(sub * 64 + j) * F_];
            #pragma unroll
            for (int r = 0; r < 4; ++r) {
                const float m = ((msk[sub][r] >> j) & 1ull) ? 1.f : 0.f;
                accN[r] = fmaf(m, h, accN[r]);
            }
        }
    }
    if (kq > 0) {
        #pragma unroll
        for (int r = 0; r < 4; ++r) sN[kq - 1][r][f] = accN[r];
    }
    __syncthreads();
    if (kq == 0) {
        #pragma unroll
        for (int r = 0; r < 4; ++r) {
            const float s = accN[r] + sN[0][r][f] + sN[1][r][f] + sN[2][r][f];
            const int deg = sDeg[0][r] + sDeg[1][r] + sDeg[2][r] + sDeg[3][r];
            nf[(size_t)(row0 + r) * F_ + f] = s / fmaxf((float)deg, 1.f);
        }
    }
}

// ---------------------------------------------------------------------------
// Kernel 2: fused score + row-MLP. 4 rows/block, 512 threads (thread = j in
// score phase; f = t&127, kq = t>>7 in mlp phase). maxc/deg stay in LDS.
// Score: elu(hi+hj) = max(x, min(Ei*Ej-1,0)) — exp amortized per (f,j).
// ---------------------------------------------------------------------------
__global__ __launch_bounds__(512) void k_main(
    const float* __restrict__ Hi, const float* __restrict__ EHi,
    const float* __restrict__ HjT, const float* __restrict__ A,
    const float* __restrict__ dW2, const float* __restrict__ db2,
    const float* __restrict__ H, const float* __restrict__ nf,
    const float* __restrict__ rW1, const float* __restrict__ rb1,
    const float* __restrict__ rW2, const float* __restrict__ rb2,
    float* __restrict__ out, float* __restrict__ maskout) {
    __shared__ float4 sU[32][9];          // [quad][0..3]=hi rows,[4..7]=Ei,[8]=w
    __shared__ float red_mx[8][4];
    __shared__ int   red_cnt[8][4];
    __shared__ float sMC[4], sDegF[4];
    __shared__ float sC[4][260];          // [r][0..127]=H, [128..255]=nf
    __shared__ float sP[3][4][F_];
    __shared__ float sL1[4][F_];
    const int t = threadIdx.x;            // == j (score phase)
    const int lane = t & 63;
    const int w = t >> 6;                 // wave 0..7
    const int f = t & 127;
    const int kq = t >> 7;                // 0..3 (mlp phase)
    const int bi0 = blockIdx.x * 4;
    const int b = bi0 >> 9;

    // --- stage mlp inputs early (latency hidden under score compute) ---
    #pragma unroll
    for (int p = 0; p < 2; ++p) {
        const int idx = t + p * 512;      // 0..1023
        const int r = idx >> 8;
        const int c = idx & 255;
        sC[r][c] = (c < F_) ? H [(size_t)(bi0 + r) * F_ + c]
                            : nf[(size_t)(bi0 + r) * F_ + (c - F_)];
    }
    // --- stage score uniforms ---
    if (t < 288) {
        const int q  = t / 9;
        const int sl = t - q * 9;
        const float* src = (sl < 4) ? (Hi  + (size_t)(bi0 + sl)     * F_ + 4 * q)
                         : (sl < 8) ? (EHi + (size_t)(bi0 + sl - 4) * F_ + 4 * q)
                                    : (dW2 + 4 * q);
        sU[q][sl] = *reinterpret_cast<const float4*>(src);
    }
    float a_r[4];
    #pragma unroll
    for (int r = 0; r < 4; ++r) a_r[r] = A[(size_t)(bi0 + r) * N_ + t];

    const float* __restrict__ hjp = HjT + (size_t)b * F_ * N_ + t;
    float hjA[4], hjB[4];
    #pragma unroll
    for (int s = 0; s < 4; ++s) hjA[s] = hjp[(size_t)s * N_];
    __syncthreads();

    float acc0 = 0.f, acc1 = 0.f, acc2 = 0.f, acc3 = 0.f;
    auto elem = [&](float hi, float ei, float wv, float hj, float ej, float& acc) {
        const float x  = hi + hj;
        const float t0 = fminf(fmaf(ei, ej, -1.f), 0.f);
        acc = fmaf(fmaxf(x, t0), wv, acc);
    };
    auto compQ = [&](int q, const float (&hjv)[4]) {
        const float4 h0 = sU[q][0], h1 = sU[q][1], h2 = sU[q][2], h3 = sU[q][3];
        const float4 e0 = sU[q][4], e1 = sU[q][5], e2 = sU[q][6], e3 = sU[q][7];
        const float4 wq = sU[q][8];
        { const float hj = hjv[0], ej = __expf(hj);
          elem(h0.x, e0.x, wq.x, hj, ej, acc0); elem(h1.x, e1.x, wq.x, hj, ej, acc1);
          elem(h2.x, e2.x, wq.x, hj, ej, acc2); elem(h3.x, e3.x, wq.x, hj, ej, acc3); }
        { const float hj = hjv[1], ej = __expf(hj);
          elem(h0.y, e0.y, wq.y, hj, ej, acc0); elem(h1.y, e1.y, wq.y, hj, ej, acc1);
          elem(h2.y, e2.y, wq.y, hj, ej, acc2); elem(h3.y, e3.y, wq.y, hj, ej, acc3); }
        { const float hj = hjv[2], ej = __expf(hj);
          elem(h0.z, e0.z, wq.z, hj, ej, acc0); elem(h1.z, e1.z, wq.z, hj, ej, acc1);
          elem(h2.z, e2.z, wq.z, hj, ej, acc2); elem(h3.z, e3.z, wq.z, hj, ej, acc3); }
        { const float hj = hjv[3], ej = __expf(hj);
          elem(h0.w, e0.w, wq.w, hj, ej, acc0); elem(h1.w, e1.w, wq.w, hj, ej, acc1);
          elem(h2.w, e2.w, wq.w, hj, ej, acc2); elem(h3.w, e3.w, wq.w, hj, ej, acc3); }
    };
    auto loadhj = [&](int q, float (&buf)[4]) {
        #pragma unroll
        for (int s = 0; s < 4; ++s) buf[s] = hjp[(size_t)(4 * q + s) * N_];
    };
    for (int q = 0; q < 32; q += 2) {
        loadhj(q + 1, hjB);
        compQ(q, hjA);
        if (q + 2 < 32) loadhj(q + 2, hjA);
        compQ(q + 1, hjB);
    }

    float accv[4] = {acc0, acc1, acc2, acc3};
    #pragma unroll
    for (int r = 0; r < 4; ++r) {
        float mx = (a_r[r] > 0.1f) ? accv[r] : -INFINITY;
        int cnt = (a_r[r] > 0.f) ? 1 : 0;
        #pragma unroll
        for (int off = 1; off < 64; off <<= 1) {
            mx = fmaxf(mx, __shfl_xor(mx, off));
            cnt += __shfl_xor(cnt, off);
        }
        if (lane == 0) { red_mx[w][r] = mx; red_cnt[w][r] = cnt; }
    }
    __syncthreads();
    if (t < 4) {
        float m = -INFINITY; int c = 0;
        #pragma unroll
        for (int ww = 0; ww < 8; ++ww) {
            m = fmaxf(m, red_mx[ww][t]);
            c += red_cnt[ww][t];
        }
        const float mc = (m > -INFINITY)
                       ? 1.f / (1.f + __expf(-(m + db2[0]))) : 0.f;
        sMC[t] = mc;
        sDegF[t] = (float)c;
        maskout[bi0 + t] = (mc > 0.5f) ? 1.f : 0.f;
    }
    // NOTE: sMC/sDegF not read until after the next barrier.

    // ---- mlp layer 1: [4 x 257] @ [257 x 128], K split across kq ----
    float macc[4];
    {
        const float bias = rb1[f];
        #pragma unroll
        for (int r = 0; r < 4; ++r) macc[r] = (kq == 0) ? bias : 0.f;
    }
    const int k0 = kq * 64;
    #pragma unroll 4
    for (int k = k0; k < k0 + 64; ++k) {
        const float wv = rW1[(size_t)k * F_ + f];
        #pragma unroll
        for (int r = 0; r < 4; ++r) macc[r] = fmaf(sC[r][k], wv, macc[r]);
    }
    __syncthreads();                      // sMC now visible; sC reads done
    if (kq == 3) {                        // k = 256: maxc column
        const float w256 = rW1[(size_t)256 * F_ + f];
        #pragma unroll
        for (int r = 0; r < 4; ++r) macc[r] = fmaf(sMC[r], w256, macc[r]);
    }
    if (kq > 0) {
        #pragma unroll
        for (int r = 0; r < 4; ++r) sP[kq - 1][r][f] = macc[r];
    }
    __syncthreads();
    if (kq == 0) {
        #pragma unroll
        for (int r = 0; r < 4; ++r)
            sL1[r][f] = elu_f(macc[r] + sP[0][r][f] + sP[1][r][f] + sP[2][r][f]);
    }
    __syncthreads();

    // ---- mlp layer 2: [4 x 128] @ [128 x 128], K split across kq ----
    float macc2[4];
    {
        const float bias2 = rb2[f];
        #pragma unroll
        for (int r = 0; r < 4; ++r) macc2[r] = (kq == 0) ? bias2 : 0.f;
    }
    const int m0k = kq * 32;
    #pragma unroll 4
    for (int k = m0k; k < m0k + 32; ++k) {
        const float wv = rW2[(size_t)k * F_ + f];
        #pragma unroll
        for (int r = 0; r < 4; ++r) macc2[r] = fmaf(sL1[r][k], wv, macc2[r]);
    }
    if (kq > 0) {
        #pragma unroll
        for (int r = 0; r < 4; ++r) sP[kq - 1][r][f] = macc2[r];
    }
    __syncthreads();
    if (kq == 0) {
        #pragma unroll
        for (int r = 0; r < 4; ++r) {
            const int row = bi0 + r;
            const float res = macc2[r] + sP[0][r][f] + sP[1][r][f] + sP[2][r][f];
            const bool upd = (sMC[r] > 0.5f) && (sDegF[r] > 0.f);
            out[(size_t)row * F_ + f] = upd ? res : sC[r][f];
        }
    }
}

// ---------------------------------------------------------------------------
extern "C" void kernel_launch(void* const* d_in, const int* in_sizes, int n_in,
                              void* d_out, int out_size, void* d_ws, size_t ws_size,
                              hipStream_t stream) {
    const float* H   = (const float*)d_in[0];
    const float* A   = (const float*)d_in[1];
    const float* dW1 = (const float*)d_in[2];
    const float* db1 = (const float*)d_in[3];
    const float* dW2 = (const float*)d_in[4];
    const float* db2 = (const float*)d_in[5];
    const float* rW1 = (const float*)d_in[6];
    const float* rb1 = (const float*)d_in[7];
    const float* rW2 = (const float*)d_in[8];
    const float* rb2 = (const float*)d_in[9];

    float* ws  = (float*)d_ws;
    float* Hi  = ws;                       // [BN][F]
    float* EHi = Hi  + BN_ * F_;           // [BN][F] exp(Hi)
    float* HjT = EHi + BN_ * F_;           // [B][F][N]
    float* nf  = HjT + BN_ * F_;           // [BN][F]

    float* out      = (float*)d_out;       // [BN][F] H_resolved
    float* mask_out = out + BN_ * F_;      // [BN] contra_mask as 0/1

    k_pre <<<BN_ / 4, 512, 0, stream>>>(H, A, dW1, db1, Hi, EHi, HjT, nf);
    k_main<<<BN_ / 4, 512, 0, stream>>>(Hi, EHi, HjT, A, dW2, db2,
                                        H, nf, rW1, rb1, rW2, rb2,
                                        out, mask_out);
}